// Round 14
// baseline (656.581 us; speedup 1.0000x reference)
//
#include <hip/hip_runtime.h>
#include <hip/hip_bf16.h>
#include <math.h>

typedef __hip_bfloat16 bf16;
typedef __attribute__((ext_vector_type(8))) short short8;
typedef __attribute__((ext_vector_type(4))) short short4v;
typedef __attribute__((ext_vector_type(4))) float f32x4;

#define DEV static __device__ __forceinline__

DEV short f2bf(float f) {
    bf16 h = __float2bfloat16(f);
    return __builtin_bit_cast(short, h);
}

DEV void glds16(const void* g, void* l) {
    __builtin_amdgcn_global_load_lds((const __attribute__((address_space(1))) void*)g,
                                     (__attribute__((address_space(3))) void*)l, 16, 0, 0);
}

// ---------------------------------------------------------------- all weight casts in one kernel
__global__ __launch_bounds__(256) void cast_all(const float* __restrict__ Wq,
                                                const float* __restrict__ Wk,
                                                const float* __restrict__ Wv,
                                                const float* __restrict__ Wo,
                                                const float* __restrict__ W1,
                                                const float* __restrict__ W2,
                                                bf16* __restrict__ wqkv, bf16* __restrict__ wo,
                                                bf16* __restrict__ w1, bf16* __restrict__ w2) {
    int i = blockIdx.x * 256 + threadIdx.x;
    const float* src;
    bf16* dst;
    int si, di;
    if (i < 786432) {
        src = (i < 262144) ? Wq : (i < 524288) ? Wk : Wv;
        si = (i < 262144) ? i : (i < 524288) ? i - 262144 : i - 524288;
        dst = wqkv; di = i;
    } else if (i < 1048576) {
        src = Wo; si = i - 786432; dst = wo; di = si;
    } else if (i < 2097152) {
        src = W1; si = i - 1048576; dst = w1; di = si;
    } else {
        src = W2; si = i - 2097152; dst = w2; di = si;
    }
    f32x4 v = ((const f32x4*)src)[si];
    short4v o;
    #pragma unroll
    for (int j = 0; j < 4; j++) o[j] = f2bf(v[j]);
    ((short4v*)dst)[di] = o;
}

// ---------------------------------------------------------------- BN eval affines (bn1, bn2, bnff)
__global__ __launch_bounds__(256) void affine_all(
    const float* __restrict__ g1, const float* __restrict__ bb1, const float* __restrict__ m1, const float* __restrict__ v1,
    const float* __restrict__ g2, const float* __restrict__ bb2, const float* __restrict__ m2, const float* __restrict__ v2,
    const float* __restrict__ gf, const float* __restrict__ bbf, const float* __restrict__ mf, const float* __restrict__ vf,
    float* __restrict__ s1, float* __restrict__ t1, float* __restrict__ s2, float* __restrict__ t2,
    float* __restrict__ sf, float* __restrict__ tf) {
    int i = blockIdx.x * 256 + threadIdx.x;
    const float *g, *b, *m, *v; float *s, *t; int j;
    if (i < 1024)      { g = g1; b = bb1; m = m1; v = v1; s = s1; t = t1; j = i; }
    else if (i < 2048) { g = g2; b = bb2; m = m2; v = v2; s = s2; t = t2; j = i - 1024; }
    else               { g = gf; b = bbf; m = mf; v = vf; s = sf; t = tf; j = i - 2048; }
    float sc = g[j] * rsqrtf(v[j] + 1e-5f);
    s[j] = sc;
    t[j] = b[j] - m[j] * sc;
}

// ---------------------------------------------------------------- LayerNorm (row=1024) + optional raw cast
__global__ __launch_bounds__(256) void ln_kernel(const float* __restrict__ x,
                                                 const float* __restrict__ g,
                                                 const float* __restrict__ b,
                                                 bf16* __restrict__ lnout,
                                                 bf16* __restrict__ rawout) {
    const int row = blockIdx.x, t = threadIdx.x;
    const float* xr = x + (size_t)row * 1024;
    f32x4 v = ((const f32x4*)xr)[t];
    float s = v[0] + v[1] + v[2] + v[3];
    float sq = v[0]*v[0] + v[1]*v[1] + v[2]*v[2] + v[3]*v[3];
    #pragma unroll
    for (int off = 1; off < 64; off <<= 1) {
        s  += __shfl_xor(s, off);
        sq += __shfl_xor(sq, off);
    }
    __shared__ float ls[4], lq[4];
    if ((t & 63) == 0) { ls[t >> 6] = s; lq[t >> 6] = sq; }
    __syncthreads();
    s = ls[0] + ls[1] + ls[2] + ls[3];
    sq = lq[0] + lq[1] + lq[2] + lq[3];
    float mu = s * (1.0f / 1024.0f);
    float rs = rsqrtf(sq * (1.0f / 1024.0f) - mu * mu + 1e-5f);
    f32x4 gg = ((const f32x4*)g)[t];
    f32x4 bb = ((const f32x4*)b)[t];
    short4v o;
    #pragma unroll
    for (int j = 0; j < 4; j++) o[j] = f2bf((v[j] - mu) * rs * gg[j] + bb[j]);
    ((short4v*)(lnout + (size_t)row * 1024))[t] = o;
    if (rawout) {
        short4v r;
        #pragma unroll
        for (int j = 0; j < 4; j++) r[j] = f2bf(v[j]);
        ((short4v*)(rawout + (size_t)row * 1024))[t] = r;
    }
}

enum { M_RESBN = 0, M_GELU = 1, M_QKV = 2 };

// ================================================================ 4-phase 256xBN 8-wave engine
template <int BN, int MODE>
__global__ __launch_bounds__(512, 2) void gemm8(
    const bf16* __restrict__ A0, const bf16* __restrict__ A1, const bf16* __restrict__ Bw,
    const float* __restrict__ b0, const float* __restrict__ b1, const float* __restrict__ b2,
    void* __restrict__ o0, void* __restrict__ o1, void* __restrict__ o2,
    const float* __restrict__ res, const float* __restrict__ sa, const float* __restrict__ ta,
    int N, int K) {
    constexpr int NB = BN / 64;
    constexpr int SB = BN * 128;
    constexpr int CW = BN / 4;
    constexpr int NF = CW / 16;
    __shared__ char smem[65536 + 2 * SB];

    const int tid = threadIdx.x, lane = tid & 63, wid = tid >> 6;
    const int gx = gridDim.x;
    const int n_wg = gx * gridDim.y;
    int lin = blockIdx.y * gx + blockIdx.x;
    lin = (lin & 7) * (n_wg >> 3) + (lin >> 3);
    const int bn = (lin % gx) * BN, bm = (lin / gx) << 8;

    const int wr = wid >> 2, wc = wid & 3;
    const int arow = lane & 15, hi = lane >> 4;
    const int xr = arow & 7;
    const int ck0 = (hi ^ xr) << 3;
    const int ck1 = ((4 + hi) ^ xr) << 3;
    const int rowA = wr * 128 + arow;
    const int rowB = wc * CW + arow;

    const bf16* Asel;
    if constexpr (MODE == M_QKV) Asel = (bn < 1024) ? A0 : A1;
    else                         Asel = A0;

    const int rS = tid >> 3;
    const int cXor = ((tid & 7) ^ (rS & 7)) << 3;
    const bf16* gA = Asel + (size_t)(bm + rS) * K + cXor;
    const bf16* gB = Bw   + (size_t)(bn + rS) * K + cXor;

    f32x4 acc[8][NF] = {};

    auto stA = [&](int t, int i) {
        glds16(gA + (size_t)i * 64 * K + t * 64,
               smem + ((t & 1) << 15) + i * 8192 + (wid << 10));
    };
    auto stB = [&](int t, int i) {
        glds16(gB + (size_t)i * 64 * K + t * 64,
               smem + 65536 + (t & 1) * SB + i * 8192 + (wid << 10));
    };

    const int NT = K >> 6;
    #pragma unroll
    for (int i = 0; i < NB; i++) stB(0, i);
    stA(0, 0); stA(0, 2); stA(0, 1); stA(0, 3);

#define PHASE(Q)                                                                              \
    do {                                                                                      \
        const short8 a00 = *(const short8*)(Ap + (rowA + (2*(Q)) * 16) * 64 + ck0);           \
        const short8 a01 = *(const short8*)(Ap + (rowA + (2*(Q)) * 16) * 64 + ck1);           \
        const short8 a10 = *(const short8*)(Ap + (rowA + (2*(Q)+1) * 16) * 64 + ck0);         \
        const short8 a11 = *(const short8*)(Ap + (rowA + (2*(Q)+1) * 16) * 64 + ck1);         \
        __builtin_amdgcn_s_setprio(1);                                                        \
        _Pragma("unroll")                                                                     \
        for (int n = 0; n < NF; n++) {                                                        \
            acc[2*(Q)][n]   = __builtin_amdgcn_mfma_f32_16x16x32_bf16(a00, bva[n], acc[2*(Q)][n], 0, 0, 0);   \
            acc[2*(Q)][n]   = __builtin_amdgcn_mfma_f32_16x16x32_bf16(a01, bvb[n], acc[2*(Q)][n], 0, 0, 0);   \
            acc[2*(Q)+1][n] = __builtin_amdgcn_mfma_f32_16x16x32_bf16(a10, bva[n], acc[2*(Q)+1][n], 0, 0, 0); \
            acc[2*(Q)+1][n] = __builtin_amdgcn_mfma_f32_16x16x32_bf16(a11, bvb[n], acc[2*(Q)+1][n], 0, 0, 0); \
        }                                                                                     \
        __builtin_amdgcn_s_setprio(0);                                                        \
    } while (0)

    for (int t = 0; t < NT; ++t) {
        const int p = t & 1;
        const bf16* Ap = (const bf16*)(smem + (p << 15));
        const bf16* Bp = (const bf16*)(smem + 65536 + p * SB);
        asm volatile("s_waitcnt vmcnt(2)" ::: "memory");
        __builtin_amdgcn_s_barrier();
        if (t + 1 < NT) {
            stB(t + 1, 0);
            if constexpr (NB == 4) stB(t + 1, 1);
        }
        short8 bva[NF], bvb[NF];
        #pragma unroll
        for (int n = 0; n < NF; n++) {
            bva[n] = *(const short8*)(Bp + (rowB + n * 16) * 64 + ck0);
            bvb[n] = *(const short8*)(Bp + (rowB + n * 16) * 64 + ck1);
        }
        PHASE(0);
        __builtin_amdgcn_s_barrier();
        if (t + 1 < NT) {
            if constexpr (NB == 4) { stB(t + 1, 2); stB(t + 1, 3); }
            else                   { stB(t + 1, 1); }
        }
        PHASE(1);
        if (t == NT - 1) asm volatile("s_waitcnt vmcnt(0)" ::: "memory");
        else if constexpr (NB == 4) asm volatile("s_waitcnt vmcnt(4)" ::: "memory");
        else                        asm volatile("s_waitcnt vmcnt(2)" ::: "memory");
        __builtin_amdgcn_s_barrier();
        if (t + 1 < NT) { stA(t + 1, 0); stA(t + 1, 2); }
        PHASE(2);
        __builtin_amdgcn_s_barrier();
        if (t + 1 < NT) { stA(t + 1, 1); stA(t + 1, 3); }
        PHASE(3);
    }
#undef PHASE

    #pragma unroll
    for (int mf = 0; mf < 8; mf++) {
        #pragma unroll
        for (int nf = 0; nf < NF; nf++) {
            const int col = bn + wc * CW + nf * 16 + arow;
            #pragma unroll
            for (int j = 0; j < 4; j++) {
                const int row = bm + wr * 128 + mf * 16 + hi * 4 + j;
                if constexpr (MODE == M_RESBN) {
                    float v = acc[mf][nf][j] + b0[col];
                    size_t idx = (size_t)row * N + col;
                    ((float*)o0)[idx] = (res[idx] + v) * sa[col] + ta[col];
                } else if constexpr (MODE == M_GELU) {
                    float v = acc[mf][nf][j] + b0[col];
                    float ge = 0.5f * v * (1.0f + erff(v * 0.70710678118f));
                    ((bf16*)o0)[(size_t)row * N + col] = __float2bfloat16(ge * sa[col] + ta[col]);
                } else {
                    const int reg = col >> 10, c = col & 1023;
                    const float bb = (reg == 0) ? b0[c] : (reg == 1) ? b1[c] : b2[c];
                    float v = acc[mf][nf][j] + bb;
                    if (reg == 0)
                        ((bf16*)o0)[(size_t)row * 1024 + c] = __float2bfloat16(v * 0.125f);
                    else if (reg == 1)
                        ((bf16*)o1)[(size_t)row * 1024 + c] = __float2bfloat16(v);
                    else
                        ((bf16*)o2)[((size_t)(row >> 10) << 20) + ((size_t)c << 10) + (row & 1023)] =
                            __float2bfloat16(v);
                }
            }
        }
    }
}

// ---------------------------------------------------------------- fused scores+softmax+attn-write+PV v8
// 256 thr / 4 waves / 16 q-rows per block (was 512/8/32). P LDS = 16x1024 bf16
// = 32KB (+0.5KB reduce) -> 4 blocks/CU co-resident (was 2 at 64KB): same 16
// waves/CU but 4 independent barrier domains -> store-drain of one block
// overlaps MFMA of the other three. All layouts (P swizzle, PV read, fragment
// maps) identical to the verified R9/R13 kernel; K-prefetch + single-barrier
// softmax retained. Wave w owns k-window [w*256,(w+1)*256) -> acc[16] (64 VGPR).
__global__ __launch_bounds__(256, 4) void fattn_kernel(const bf16* __restrict__ q,
                                                       const bf16* __restrict__ k,
                                                       const bf16* __restrict__ vT,
                                                       const int* __restrict__ mask,
                                                       float* __restrict__ attn,
                                                       bf16* __restrict__ ctx) {
    const int bh = blockIdx.y, b = bh >> 4, h = bh & 15;
    const int q0 = blockIdx.x << 4;
    const int tid = threadIdx.x, lane = tid & 63, wid = tid >> 6;
    const int kb = wid << 8;                 // wave's 256-key window
    const int arow = lane & 15, hi = lane >> 4, koff = hi << 3;
    const int rbase = hi << 2;

    __shared__ char smem[33280];             // P 32K | redm 256B | reds 256B
    bf16* Plds = (bf16*)smem;
    float* redm = (float*)(smem + 32768);    // [16][4] wave-local max
    float* reds = (float*)(smem + 33024);    // [16][4] wave-local sum

    // ---- QK^T over full dk=64, 1-deep K prefetch ----
    const bf16* qp = q + ((size_t)((b << 10) + q0 + arow) << 10) + (h << 6);
    const short8 qf  = *(const short8*)(qp + koff);
    const short8 qf2 = *(const short8*)(qp + 32 + koff);

    f32x4 acc[16];
    #pragma unroll
    for (int n = 0; n < 16; n++) acc[n] = (f32x4){0.f, 0.f, 0.f, 0.f};

    const bf16* kpBase = k + ((size_t)((b << 10) + kb + arow) << 10) + (h << 6);
    short8 kf  = *(const short8*)(kpBase + koff);
    short8 kf2 = *(const short8*)(kpBase + 32 + koff);
    #pragma unroll
    for (int n = 0; n < 16; n++) {
        short8 kfn, kf2n;
        if (n < 15) {
            const bf16* kp = kpBase + ((size_t)(n + 1) << 14);   // +16 rows of 1024
            kfn  = *(const short8*)(kp + koff);
            kf2n = *(const short8*)(kp + 32 + koff);
        }
        acc[n] = __builtin_amdgcn_mfma_f32_16x16x32_bf16(qf,  kf,  acc[n], 0, 0, 0);
        acc[n] = __builtin_amdgcn_mfma_f32_16x16x32_bf16(qf2, kf2, acc[n], 0, 0, 0);
        kf = kfn; kf2 = kf2n;
    }

    // ---- mask + wave-local row max ----
    float rmax[4];
    #pragma unroll
    for (int j = 0; j < 4; j++) rmax[j] = -3.0e38f;
    #pragma unroll
    for (int n = 0; n < 16; n++) {
        const float madd = mask[(b << 10) + kb + (n << 4) + arow] ? 0.0f : -1e9f;
        #pragma unroll
        for (int j = 0; j < 4; j++) {
            acc[n][j] += madd;
            rmax[j] = fmaxf(rmax[j], acc[n][j]);
        }
    }
    #pragma unroll
    for (int off = 1; off < 16; off <<= 1)
        #pragma unroll
        for (int j = 0; j < 4; j++) rmax[j] = fmaxf(rmax[j], __shfl_xor(rmax[j], off));

    // ---- exp (vs wave-local max) + wave-local sum ----
    float rsum[4] = {0.f, 0.f, 0.f, 0.f};
    #pragma unroll
    for (int n = 0; n < 16; n++)
        #pragma unroll
        for (int j = 0; j < 4; j++) {
            float p = __expf(acc[n][j] - rmax[j]);
            acc[n][j] = p;
            rsum[j] += p;
        }
    #pragma unroll
    for (int off = 1; off < 16; off <<= 1)
        #pragma unroll
        for (int j = 0; j < 4; j++) rsum[j] += __shfl_xor(rsum[j], off);

    // ---- ONE barrier round: publish (ml, sl) per wave ----
    if (arow == 0) {
        #pragma unroll
        for (int j = 0; j < 4; j++) {
            const int qr = rbase + j;
            redm[(qr << 2) + wid] = rmax[j];
            reds[(qr << 2) + wid] = rsum[j];
        }
    }
    __syncthreads();

    // global max + combined sum; fold into per-row store scale
    float fscale[4];
    #pragma unroll
    for (int j = 0; j < 4; j++) {
        const int qr = rbase + j;
        f32x4 m0 = *(const f32x4*)(redm + (qr << 2));
        f32x4 s0 = *(const f32x4*)(reds + (qr << 2));
        float gm = fmaxf(fmaxf(m0[0], m0[1]), fmaxf(m0[2], m0[3]));
        float S = s0[0] * __expf(m0[0] - gm) + s0[1] * __expf(m0[1] - gm) +
                  s0[2] * __expf(m0[2] - gm) + s0[3] * __expf(m0[3] - gm);
        fscale[j] = __expf(rmax[j] - gm) / S;
    }

    // ---- normalize + write attn (global f32) + P tile (LDS bf16, XOR-swizzled) ----
    const size_t obase = (((size_t)bh << 10) + q0) << 10;
    #pragma unroll
    for (int j = 0; j < 4; j++) {
        const int qr = rbase + j;
        float* orow = attn + obase + ((size_t)qr << 10) + kb;
        char* prow = (char*)Plds + (qr << 11);
        const int rx = (qr & 7) << 4;
        const float iv = fscale[j];
        #pragma unroll
        for (int n = 0; n < 16; n++) {
            float p = acc[n][j] * iv;
            orow[(n << 4) + arow] = p;
            *(bf16*)(prow + ((((kb + (n << 4) + arow)) << 1) ^ rx)) = __float2bfloat16(p);
        }
    }

    // all waves' P LDS writes visible; attn global writes keep draining (no vmcnt wait)
    asm volatile("s_waitcnt lgkmcnt(0)" ::: "memory");
    __builtin_amdgcn_s_barrier();
    __builtin_amdgcn_sched_barrier(0);

    // ---- PV: wave dh -> full ctx[16q x 16dk] over 1024 keys ----
    const int dh = wid;
    const char* pbase = (char*)Plds + (arow << 11);          // P row = q = arow
    const int prx = (arow & 7) << 4;
    const bf16* vrow = vT + ((size_t)((b << 10) + (h << 6) + (dh << 4) + arow) << 10);
    f32x4 acc2 = (f32x4){0.f, 0.f, 0.f, 0.f};
    #pragma unroll 8
    for (int kt = 0; kt < 32; kt++) {
        short8 af  = *(const short8*)(pbase + (((kt << 6) + (hi << 4)) ^ prx));
        short8 bf2 = *(const short8*)(vrow + (kt << 5) + koff);
        acc2 = __builtin_amdgcn_mfma_f32_16x16x32_bf16(af, bf2, acc2, 0, 0, 0);
    }

    #pragma unroll
    for (int j = 0; j < 4; j++) {
        const int row = q0 + rbase + j;
        ctx[((size_t)((b << 10) + row) << 10) + (h << 6) + (dh << 4) + arow] =
            __float2bfloat16(acc2[j]);
    }
}

// ---------------------------------------------------------------- launch
extern "C" void kernel_launch(void* const* d_in, const int* in_sizes, int n_in,
                              void* d_out, int out_size, void* d_ws, size_t ws_size,
                              hipStream_t stream) {
    (void)in_sizes; (void)n_in; (void)out_size; (void)ws_size;
    const float* x   = (const float*)d_in[0];
    const int*   mask= (const int*)d_in[1];
    const float* Wq  = (const float*)d_in[2];  const float* bq  = (const float*)d_in[3];
    const float* Wk  = (const float*)d_in[4];  const float* bk  = (const float*)d_in[5];
    const float* Wv  = (const float*)d_in[6];  const float* bv  = (const float*)d_in[7];
    const float* Wo  = (const float*)d_in[8];  const float* bo  = (const float*)d_in[9];
    const float* lag = (const float*)d_in[10]; const float* lab = (const float*)d_in[11];
    const float* W1  = (const float*)d_in[12]; const float* b1  = (const float*)d_in[13];
    const float* W2  = (const float*)d_in[14]; const float* b2  = (const float*)d_in[15];
    const float* lfg = (const float*)d_in[16]; const float* lfb = (const float*)d_in[17];
    const float* bffg= (const float*)d_in[18]; const float* bffb= (const float*)d_in[19];
    const float* bffm= (const float*)d_in[20]; const float* bffv= (const float*)d_in[21];
    const float* b1g = (const float*)d_in[22]; const float* b1b = (const float*)d_in[23];
    const float* b1m = (const float*)d_in[24]; const float* b1v = (const float*)d_in[25];
    const float* b2g = (const float*)d_in[26]; const float* b2b = (const float*)d_in[27];
    const float* b2m = (const float*)d_in[28]; const float* b2v = (const float*)d_in[29];

    char* ws = (char*)d_ws;
    const size_t MB = 1024 * 1024;
    bf16* wqkv_bf = (bf16*)(ws);               // 6 MB  (3072 x 1024)
    bf16* wo_bf   = (bf16*)(ws + 6 * MB);      // 2 MB
    bf16* w1_bf   = (bf16*)(ws + 8 * MB);      // 8 MB
    bf16* w2_bf   = (bf16*)(ws + 16 * MB);     // 8 MB
    float* s1  = (float*)(ws + 24 * MB); float* t1  = s1 + 1024;
    float* s2  = t1 + 1024;              float* t2  = s2 + 1024;
    float* sff = t2 + 1024;              float* tff = sff + 4096;
    bf16* x_bf   = (bf16*)(ws + 25 * MB);
    bf16* xq_bf  = (bf16*)(ws + 41 * MB);
    bf16* q_bf   = (bf16*)(ws + 57 * MB);
    bf16* k_bf   = (bf16*)(ws + 73 * MB);
    bf16* vT_bf  = (bf16*)(ws + 89 * MB);
    bf16* ctx_bf = (bf16*)(ws + 105 * MB);
    float* x1    = (float*)(ws + 121 * MB);    // 32 MB f32
    bf16* xn_bf  = (bf16*)(ws + 153 * MB);
    bf16* h_bf   = (bf16*)(ws + 169 * MB);     // 64 MB, ends at 233 MB

    float* out_x    = (float*)d_out;
    float* out_attn = out_x + (size_t)8 * 1024 * 1024;

    cast_all<<<12288, 256, 0, stream>>>(Wq, Wk, Wv, Wo, W1, W2, wqkv_bf, wo_bf, w1_bf, w2_bf);
    affine_all<<<24, 256, 0, stream>>>(b1g, b1b, b1m, b1v, b2g, b2b, b2m, b2v,
                                       bffg, bffb, bffm, bffv, s1, t1, s2, t2, sff, tff);

    // LN(x) (for q) + raw cast (for k,v)
    ln_kernel<<<8192, 256, 0, stream>>>(x, lag, lab, xq_bf, x_bf);

    // fused q/k/v projection — 768 blocks (3/CU exact)
    gemm8<128, M_QKV><<<dim3(24, 32), 512, 0, stream>>>(
        xq_bf, x_bf, wqkv_bf, bq, bk, bv, q_bf, k_bf, vT_bf, nullptr, nullptr, nullptr, 1024, 1024);

    // fused scores+softmax (-> d_out attn) + PV via shared LDS P (-> ctx)
    fattn_kernel<<<dim3(64, 128), 256, 0, stream>>>(q_bf, k_bf, vT_bf, mask, out_attn, ctx_bf);

    // attn_out proj + residual + bn1 -> x1 (f32) — 256 blocks
    gemm8<128, M_RESBN><<<dim3(8, 32), 512, 0, stream>>>(
        ctx_bf, nullptr, wo_bf, bo, nullptr, nullptr, x1, nullptr, nullptr, x, s1, t1, 1024, 1024);

    // FFN: LN -> W1+gelu+bnff (512 blocks) -> W2 + residual + bn2 (256 blocks)
    ln_kernel<<<8192, 256, 0, stream>>>(x1, lfg, lfb, xn_bf, nullptr);
    gemm8<256, M_GELU><<<dim3(16, 32), 512, 0, stream>>>(
        xn_bf, nullptr, w1_bf, b1, nullptr, nullptr, h_bf, nullptr, nullptr, nullptr, sff, tff, 4096, 1024);
    gemm8<128, M_RESBN><<<dim3(8, 32), 512, 0, stream>>>(
        h_bf, nullptr, w2_bf, b2, nullptr, nullptr, out_x, nullptr, nullptr, x1, s2, t2, 1024, 4096);
}

// Round 15
// 606.513 us; speedup vs baseline: 1.0825x; 1.0825x over previous
//
#include <hip/hip_runtime.h>
#include <hip/hip_bf16.h>
#include <math.h>

typedef __hip_bfloat16 bf16;
typedef __attribute__((ext_vector_type(8))) short short8;
typedef __attribute__((ext_vector_type(4))) short short4v;
typedef __attribute__((ext_vector_type(4))) float f32x4;

#define DEV static __device__ __forceinline__

DEV short f2bf(float f) {
    bf16 h = __float2bfloat16(f);
    return __builtin_bit_cast(short, h);
}

DEV void glds16(const void* g, void* l) {
    __builtin_amdgcn_global_load_lds((const __attribute__((address_space(1))) void*)g,
                                     (__attribute__((address_space(3))) void*)l, 16, 0, 0);
}

// ---------------------------------------------------------------- all weight casts in one kernel
__global__ __launch_bounds__(256) void cast_all(const float* __restrict__ Wq,
                                                const float* __restrict__ Wk,
                                                const float* __restrict__ Wv,
                                                const float* __restrict__ Wo,
                                                const float* __restrict__ W1,
                                                const float* __restrict__ W2,
                                                bf16* __restrict__ wqkv, bf16* __restrict__ wo,
                                                bf16* __restrict__ w1, bf16* __restrict__ w2) {
    int i = blockIdx.x * 256 + threadIdx.x;
    const float* src;
    bf16* dst;
    int si, di;
    if (i < 786432) {
        src = (i < 262144) ? Wq : (i < 524288) ? Wk : Wv;
        si = (i < 262144) ? i : (i < 524288) ? i - 262144 : i - 524288;
        dst = wqkv; di = i;
    } else if (i < 1048576) {
        src = Wo; si = i - 786432; dst = wo; di = si;
    } else if (i < 2097152) {
        src = W1; si = i - 1048576; dst = w1; di = si;
    } else {
        src = W2; si = i - 2097152; dst = w2; di = si;
    }
    f32x4 v = ((const f32x4*)src)[si];
    short4v o;
    #pragma unroll
    for (int j = 0; j < 4; j++) o[j] = f2bf(v[j]);
    ((short4v*)dst)[di] = o;
}

// ---------------------------------------------------------------- BN eval affines (bn1, bn2, bnff)
__global__ __launch_bounds__(256) void affine_all(
    const float* __restrict__ g1, const float* __restrict__ bb1, const float* __restrict__ m1, const float* __restrict__ v1,
    const float* __restrict__ g2, const float* __restrict__ bb2, const float* __restrict__ m2, const float* __restrict__ v2,
    const float* __restrict__ gf, const float* __restrict__ bbf, const float* __restrict__ mf, const float* __restrict__ vf,
    float* __restrict__ s1, float* __restrict__ t1, float* __restrict__ s2, float* __restrict__ t2,
    float* __restrict__ sf, float* __restrict__ tf) {
    int i = blockIdx.x * 256 + threadIdx.x;
    const float *g, *b, *m, *v; float *s, *t; int j;
    if (i < 1024)      { g = g1; b = bb1; m = m1; v = v1; s = s1; t = t1; j = i; }
    else if (i < 2048) { g = g2; b = bb2; m = m2; v = v2; s = s2; t = t2; j = i - 1024; }
    else               { g = gf; b = bbf; m = mf; v = vf; s = sf; t = tf; j = i - 2048; }
    float sc = g[j] * rsqrtf(v[j] + 1e-5f);
    s[j] = sc;
    t[j] = b[j] - m[j] * sc;
}

// ---------------------------------------------------------------- LayerNorm (row=1024) + optional raw cast
__global__ __launch_bounds__(256) void ln_kernel(const float* __restrict__ x,
                                                 const float* __restrict__ g,
                                                 const float* __restrict__ b,
                                                 bf16* __restrict__ lnout,
                                                 bf16* __restrict__ rawout) {
    const int row = blockIdx.x, t = threadIdx.x;
    const float* xr = x + (size_t)row * 1024;
    f32x4 v = ((const f32x4*)xr)[t];
    float s = v[0] + v[1] + v[2] + v[3];
    float sq = v[0]*v[0] + v[1]*v[1] + v[2]*v[2] + v[3]*v[3];
    #pragma unroll
    for (int off = 1; off < 64; off <<= 1) {
        s  += __shfl_xor(s, off);
        sq += __shfl_xor(sq, off);
    }
    __shared__ float ls[4], lq[4];
    if ((t & 63) == 0) { ls[t >> 6] = s; lq[t >> 6] = sq; }
    __syncthreads();
    s = ls[0] + ls[1] + ls[2] + ls[3];
    sq = lq[0] + lq[1] + lq[2] + lq[3];
    float mu = s * (1.0f / 1024.0f);
    float rs = rsqrtf(sq * (1.0f / 1024.0f) - mu * mu + 1e-5f);
    f32x4 gg = ((const f32x4*)g)[t];
    f32x4 bb = ((const f32x4*)b)[t];
    short4v o;
    #pragma unroll
    for (int j = 0; j < 4; j++) o[j] = f2bf((v[j] - mu) * rs * gg[j] + bb[j]);
    ((short4v*)(lnout + (size_t)row * 1024))[t] = o;
    if (rawout) {
        short4v r;
        #pragma unroll
        for (int j = 0; j < 4; j++) r[j] = f2bf(v[j]);
        ((short4v*)(rawout + (size_t)row * 1024))[t] = r;
    }
}

enum { M_RESBN = 0, M_GELU = 1, M_QKV = 2 };

// ================================================================ 4-phase 256x256 engine (W1 only)
template <int BN, int MODE>
__global__ __launch_bounds__(512, 2) void gemm8(
    const bf16* __restrict__ A0, const bf16* __restrict__ A1, const bf16* __restrict__ Bw,
    const float* __restrict__ b0, const float* __restrict__ b1, const float* __restrict__ b2,
    void* __restrict__ o0, void* __restrict__ o1, void* __restrict__ o2,
    const float* __restrict__ res, const float* __restrict__ sa, const float* __restrict__ ta,
    int N, int K) {
    constexpr int NB = BN / 64;
    constexpr int SB = BN * 128;
    constexpr int CW = BN / 4;
    constexpr int NF = CW / 16;
    __shared__ char smem[65536 + 2 * SB];

    const int tid = threadIdx.x, lane = tid & 63, wid = tid >> 6;
    const int gx = gridDim.x;
    const int n_wg = gx * gridDim.y;
    int lin = blockIdx.y * gx + blockIdx.x;
    lin = (lin & 7) * (n_wg >> 3) + (lin >> 3);
    const int bn = (lin % gx) * BN, bm = (lin / gx) << 8;

    const int wr = wid >> 2, wc = wid & 3;
    const int arow = lane & 15, hi = lane >> 4;
    const int xr = arow & 7;
    const int ck0 = (hi ^ xr) << 3;
    const int ck1 = ((4 + hi) ^ xr) << 3;
    const int rowA = wr * 128 + arow;
    const int rowB = wc * CW + arow;

    const bf16* Asel;
    if constexpr (MODE == M_QKV) Asel = (bn < 1024) ? A0 : A1;
    else                         Asel = A0;

    const int rS = tid >> 3;
    const int cXor = ((tid & 7) ^ (rS & 7)) << 3;
    const bf16* gA = Asel + (size_t)(bm + rS) * K + cXor;
    const bf16* gB = Bw   + (size_t)(bn + rS) * K + cXor;

    f32x4 acc[8][NF] = {};

    auto stA = [&](int t, int i) {
        glds16(gA + (size_t)i * 64 * K + t * 64,
               smem + ((t & 1) << 15) + i * 8192 + (wid << 10));
    };
    auto stB = [&](int t, int i) {
        glds16(gB + (size_t)i * 64 * K + t * 64,
               smem + 65536 + (t & 1) * SB + i * 8192 + (wid << 10));
    };

    const int NT = K >> 6;
    #pragma unroll
    for (int i = 0; i < NB; i++) stB(0, i);
    stA(0, 0); stA(0, 2); stA(0, 1); stA(0, 3);

#define PHASE(Q)                                                                              \
    do {                                                                                      \
        const short8 a00 = *(const short8*)(Ap + (rowA + (2*(Q)) * 16) * 64 + ck0);           \
        const short8 a01 = *(const short8*)(Ap + (rowA + (2*(Q)) * 16) * 64 + ck1);           \
        const short8 a10 = *(const short8*)(Ap + (rowA + (2*(Q)+1) * 16) * 64 + ck0);         \
        const short8 a11 = *(const short8*)(Ap + (rowA + (2*(Q)+1) * 16) * 64 + ck1);         \
        __builtin_amdgcn_s_setprio(1);                                                        \
        _Pragma("unroll")                                                                     \
        for (int n = 0; n < NF; n++) {                                                        \
            acc[2*(Q)][n]   = __builtin_amdgcn_mfma_f32_16x16x32_bf16(a00, bva[n], acc[2*(Q)][n], 0, 0, 0);   \
            acc[2*(Q)][n]   = __builtin_amdgcn_mfma_f32_16x16x32_bf16(a01, bvb[n], acc[2*(Q)][n], 0, 0, 0);   \
            acc[2*(Q)+1][n] = __builtin_amdgcn_mfma_f32_16x16x32_bf16(a10, bva[n], acc[2*(Q)+1][n], 0, 0, 0); \
            acc[2*(Q)+1][n] = __builtin_amdgcn_mfma_f32_16x16x32_bf16(a11, bvb[n], acc[2*(Q)+1][n], 0, 0, 0); \
        }                                                                                     \
        __builtin_amdgcn_s_setprio(0);                                                        \
    } while (0)

    for (int t = 0; t < NT; ++t) {
        const int p = t & 1;
        const bf16* Ap = (const bf16*)(smem + (p << 15));
        const bf16* Bp = (const bf16*)(smem + 65536 + p * SB);
        asm volatile("s_waitcnt vmcnt(2)" ::: "memory");
        __builtin_amdgcn_s_barrier();
        if (t + 1 < NT) {
            stB(t + 1, 0);
            if constexpr (NB == 4) stB(t + 1, 1);
        }
        short8 bva[NF], bvb[NF];
        #pragma unroll
        for (int n = 0; n < NF; n++) {
            bva[n] = *(const short8*)(Bp + (rowB + n * 16) * 64 + ck0);
            bvb[n] = *(const short8*)(Bp + (rowB + n * 16) * 64 + ck1);
        }
        PHASE(0);
        __builtin_amdgcn_s_barrier();
        if (t + 1 < NT) {
            if constexpr (NB == 4) { stB(t + 1, 2); stB(t + 1, 3); }
            else                   { stB(t + 1, 1); }
        }
        PHASE(1);
        if (t == NT - 1) asm volatile("s_waitcnt vmcnt(0)" ::: "memory");
        else if constexpr (NB == 4) asm volatile("s_waitcnt vmcnt(4)" ::: "memory");
        else                        asm volatile("s_waitcnt vmcnt(2)" ::: "memory");
        __builtin_amdgcn_s_barrier();
        if (t + 1 < NT) { stA(t + 1, 0); stA(t + 1, 2); }
        PHASE(2);
        __builtin_amdgcn_s_barrier();
        if (t + 1 < NT) { stA(t + 1, 1); stA(t + 1, 3); }
        PHASE(3);
    }
#undef PHASE

    #pragma unroll
    for (int mf = 0; mf < 8; mf++) {
        #pragma unroll
        for (int nf = 0; nf < NF; nf++) {
            const int col = bn + wc * CW + nf * 16 + arow;
            #pragma unroll
            for (int j = 0; j < 4; j++) {
                const int row = bm + wr * 128 + mf * 16 + hi * 4 + j;
                if constexpr (MODE == M_RESBN) {
                    float v = acc[mf][nf][j] + b0[col];
                    size_t idx = (size_t)row * N + col;
                    ((float*)o0)[idx] = (res[idx] + v) * sa[col] + ta[col];
                } else if constexpr (MODE == M_GELU) {
                    float v = acc[mf][nf][j] + b0[col];
                    float ge = 0.5f * v * (1.0f + erff(v * 0.70710678118f));
                    ((bf16*)o0)[(size_t)row * N + col] = __float2bfloat16(ge * sa[col] + ta[col]);
                } else {
                    const int reg = col >> 10, c = col & 1023;
                    const float bb = (reg == 0) ? b0[c] : (reg == 1) ? b1[c] : b2[c];
                    float v = acc[mf][nf][j] + bb;
                    if (reg == 0)
                        ((bf16*)o0)[(size_t)row * 1024 + c] = __float2bfloat16(v * 0.125f);
                    else if (reg == 1)
                        ((bf16*)o1)[(size_t)row * 1024 + c] = __float2bfloat16(v);
                    else
                        ((bf16*)o2)[((size_t)(row >> 10) << 20) + ((size_t)c << 10) + (row & 1023)] =
                            __float2bfloat16(v);
                }
            }
        }
    }
}

// ================================================================ 3-slot ring 256x128 engine (QKV, Wo, W2)
// BK=64, 8 waves 2Mx4N, wave-tile 128x32 (MF=8, NF=2). LDS: A 3x32KB @0,
// B 3x16KB @98304 (144KB). Stage tile t+2 during t -> ONE vmcnt(6) + ONE
// barrier per K-tile; tile t's 6 loads were issued a full tile earlier
// (>= HBM latency cover). No intra-tile barriers: slot (t+2)%3 disjoint from
// t,t+1; entry barrier orders overwrite of slot(t-1) vs its readers.
template <int MODE>
__global__ __launch_bounds__(512, 2) void gemm3s(
    const bf16* __restrict__ A0, const bf16* __restrict__ A1, const bf16* __restrict__ Bw,
    const float* __restrict__ b0, const float* __restrict__ b1, const float* __restrict__ b2,
    void* __restrict__ o0, void* __restrict__ o1, void* __restrict__ o2,
    const float* __restrict__ res, const float* __restrict__ sa, const float* __restrict__ ta,
    int N, int K) {
    __shared__ char smem[147456];

    const int tid = threadIdx.x, lane = tid & 63, wid = tid >> 6;
    const int gx = gridDim.x;
    const int n_wg = gx * gridDim.y;
    int lin = blockIdx.y * gx + blockIdx.x;
    lin = (lin & 7) * (n_wg >> 3) + (lin >> 3);    // XCD swizzle (n_wg % 8 == 0)
    const int bn = (lin % gx) << 7, bm = (lin / gx) << 8;

    const int wr = wid >> 2, wc = wid & 3;
    const int arow = lane & 15, hi = lane >> 4;
    const int xr = arow & 7;
    const int ck0 = (hi ^ xr) << 3;
    const int ck1 = ((4 + hi) ^ xr) << 3;
    const int rowA = wr * 128 + arow;
    const int rowB = wc * 32 + arow;

    const bf16* Asel;
    if constexpr (MODE == M_QKV) Asel = (bn < 1024) ? A0 : A1;
    else                         Asel = A0;

    const int rS = tid >> 3;
    const int cXor = ((tid & 7) ^ (rS & 7)) << 3;
    const bf16* gA = Asel + (size_t)(bm + rS) * K + cXor;
    const bf16* gB = Bw   + (size_t)(bn + rS) * K + cXor;

    f32x4 acc[8][2] = {};

    auto stA = [&](int t, int i) {
        glds16(gA + (size_t)i * 64 * K + t * 64,
               smem + (t % 3) * 32768 + i * 8192 + (wid << 10));
    };
    auto stB = [&](int t, int i) {
        glds16(gB + (size_t)i * 64 * K + t * 64,
               smem + 98304 + (t % 3) * 16384 + i * 8192 + (wid << 10));
    };

    const int NT = K >> 6;
    // prologue: tiles 0 and 1 fully staged (6 issues each)
    stB(0, 0); stB(0, 1); stA(0, 0); stA(0, 2); stA(0, 1); stA(0, 3);
    stB(1, 0); stB(1, 1); stA(1, 0); stA(1, 2); stA(1, 1); stA(1, 3);

#define PHASE3(Q)                                                                             \
    do {                                                                                      \
        const short8 a00 = *(const short8*)(Ap + (rowA + (2*(Q)) * 16) * 64 + ck0);           \
        const short8 a01 = *(const short8*)(Ap + (rowA + (2*(Q)) * 16) * 64 + ck1);           \
        const short8 a10 = *(const short8*)(Ap + (rowA + (2*(Q)+1) * 16) * 64 + ck0);         \
        const short8 a11 = *(const short8*)(Ap + (rowA + (2*(Q)+1) * 16) * 64 + ck1);         \
        __builtin_amdgcn_s_setprio(1);                                                        \
        _Pragma("unroll")                                                                     \
        for (int n = 0; n < 2; n++) {                                                         \
            acc[2*(Q)][n]   = __builtin_amdgcn_mfma_f32_16x16x32_bf16(a00, bva[n], acc[2*(Q)][n], 0, 0, 0);   \
            acc[2*(Q)][n]   = __builtin_amdgcn_mfma_f32_16x16x32_bf16(a01, bvb[n], acc[2*(Q)][n], 0, 0, 0);   \
            acc[2*(Q)+1][n] = __builtin_amdgcn_mfma_f32_16x16x32_bf16(a10, bva[n], acc[2*(Q)+1][n], 0, 0, 0); \
            acc[2*(Q)+1][n] = __builtin_amdgcn_mfma_f32_16x16x32_bf16(a11, bvb[n], acc[2*(Q)+1][n], 0, 0, 0); \
        }                                                                                     \
        __builtin_amdgcn_s_setprio(0);                                                        \
    } while (0)

    for (int t = 0; t < NT; ++t) {
        const bf16* Ap = (const bf16*)(smem + (t % 3) * 32768);
        const bf16* Bp = (const bf16*)(smem + 98304 + (t % 3) * 16384);
        // one counted wait per tile: drain tile t's 6 loads (issued during t-2/prologue),
        // keep tile t+1's 6 in flight
        if (t >= NT - 1) asm volatile("s_waitcnt vmcnt(0)" ::: "memory");
        else             asm volatile("s_waitcnt vmcnt(6)" ::: "memory");
        __builtin_amdgcn_s_barrier();
        if (t + 2 < NT) { stB(t + 2, 0); stB(t + 2, 1); }
        short8 bva[2], bvb[2];
        #pragma unroll
        for (int n = 0; n < 2; n++) {
            bva[n] = *(const short8*)(Bp + (rowB + n * 16) * 64 + ck0);
            bvb[n] = *(const short8*)(Bp + (rowB + n * 16) * 64 + ck1);
        }
        PHASE3(0);
        PHASE3(1);
        if (t + 2 < NT) { stA(t + 2, 0); stA(t + 2, 2); }
        PHASE3(2);
        if (t + 2 < NT) { stA(t + 2, 1); stA(t + 2, 3); }
        PHASE3(3);
    }
#undef PHASE3

    #pragma unroll
    for (int mf = 0; mf < 8; mf++) {
        #pragma unroll
        for (int nf = 0; nf < 2; nf++) {
            const int col = bn + wc * 32 + nf * 16 + arow;
            #pragma unroll
            for (int j = 0; j < 4; j++) {
                const int row = bm + wr * 128 + mf * 16 + hi * 4 + j;
                if constexpr (MODE == M_RESBN) {
                    float v = acc[mf][nf][j] + b0[col];
                    size_t idx = (size_t)row * N + col;
                    ((float*)o0)[idx] = (res[idx] + v) * sa[col] + ta[col];
                } else if constexpr (MODE == M_GELU) {
                    float v = acc[mf][nf][j] + b0[col];
                    float ge = 0.5f * v * (1.0f + erff(v * 0.70710678118f));
                    ((bf16*)o0)[(size_t)row * N + col] = __float2bfloat16(ge * sa[col] + ta[col]);
                } else {
                    const int reg = col >> 10, c = col & 1023;
                    const float bb = (reg == 0) ? b0[c] : (reg == 1) ? b1[c] : b2[c];
                    float v = acc[mf][nf][j] + bb;
                    if (reg == 0)
                        ((bf16*)o0)[(size_t)row * 1024 + c] = __float2bfloat16(v * 0.125f);
                    else if (reg == 1)
                        ((bf16*)o1)[(size_t)row * 1024 + c] = __float2bfloat16(v);
                    else
                        ((bf16*)o2)[((size_t)(row >> 10) << 20) + ((size_t)c << 10) + (row & 1023)] =
                            __float2bfloat16(v);
                }
            }
        }
    }
}

// ---------------------------------------------------------------- fused scores+softmax+attn-write+PV (R13 best)
__global__ __launch_bounds__(512, 4) void fattn_kernel(const bf16* __restrict__ q,
                                                       const bf16* __restrict__ k,
                                                       const bf16* __restrict__ vT,
                                                       const int* __restrict__ mask,
                                                       float* __restrict__ attn,
                                                       bf16* __restrict__ ctx) {
    const int bh = blockIdx.y, b = bh >> 4, h = bh & 15;
    const int q0 = blockIdx.x << 5;
    const int tid = threadIdx.x, lane = tid & 63, wid = tid >> 6;
    const int kb = wid << 7;
    const int arow = lane & 15, hi = lane >> 4, koff = hi << 3;
    const int rbase = hi << 2;

    __shared__ char smem[67584];
    bf16* Plds = (bf16*)smem;
    float* redm = (float*)(smem + 65536);
    float* reds = (float*)(smem + 66560);

    short8 qf[2], qf2[2];
    #pragma unroll
    for (int m = 0; m < 2; m++) {
        const bf16* qp = q + ((size_t)((b << 10) + q0 + (m << 4) + arow) << 10) + (h << 6);
        qf[m]  = *(const short8*)(qp + koff);
        qf2[m] = *(const short8*)(qp + 32 + koff);
    }

    f32x4 acc[2][8];
    #pragma unroll
    for (int m = 0; m < 2; m++)
        #pragma unroll
        for (int n = 0; n < 8; n++) acc[m][n] = (f32x4){0.f, 0.f, 0.f, 0.f};

    const bf16* kpBase = k + ((size_t)((b << 10) + kb + arow) << 10) + (h << 6);
    short8 kf  = *(const short8*)(kpBase + koff);
    short8 kf2 = *(const short8*)(kpBase + 32 + koff);
    #pragma unroll
    for (int n = 0; n < 8; n++) {
        short8 kfn, kf2n;
        if (n < 7) {
            const bf16* kp = kpBase + ((size_t)(n + 1) << 14);
            kfn  = *(const short8*)(kp + koff);
            kf2n = *(const short8*)(kp + 32 + koff);
        }
        acc[0][n] = __builtin_amdgcn_mfma_f32_16x16x32_bf16(qf[0],  kf,  acc[0][n], 0, 0, 0);
        acc[0][n] = __builtin_amdgcn_mfma_f32_16x16x32_bf16(qf2[0], kf2, acc[0][n], 0, 0, 0);
        acc[1][n] = __builtin_amdgcn_mfma_f32_16x16x32_bf16(qf[1],  kf,  acc[1][n], 0, 0, 0);
        acc[1][n] = __builtin_amdgcn_mfma_f32_16x16x32_bf16(qf2[1], kf2, acc[1][n], 0, 0, 0);
        kf = kfn; kf2 = kf2n;
    }

    float rmax[2][4];
    #pragma unroll
    for (int m = 0; m < 2; m++)
        #pragma unroll
        for (int j = 0; j < 4; j++) rmax[m][j] = -3.0e38f;

    #pragma unroll
    for (int n = 0; n < 8; n++) {
        const float madd = mask[(b << 10) + kb + (n << 4) + arow] ? 0.0f : -1e9f;
        #pragma unroll
        for (int m = 0; m < 2; m++)
            #pragma unroll
            for (int j = 0; j < 4; j++) {
                acc[m][n][j] += madd;
                rmax[m][j] = fmaxf(rmax[m][j], acc[m][n][j]);
            }
    }
    #pragma unroll
    for (int off = 1; off < 16; off <<= 1)
        #pragma unroll
        for (int m = 0; m < 2; m++)
            #pragma unroll
            for (int j = 0; j < 4; j++) rmax[m][j] = fmaxf(rmax[m][j], __shfl_xor(rmax[m][j], off));

    float rsum[2][4] = {};
    #pragma unroll
    for (int n = 0; n < 8; n++)
        #pragma unroll
        for (int m = 0; m < 2; m++)
            #pragma unroll
            for (int j = 0; j < 4; j++) {
                float p = __expf(acc[m][n][j] - rmax[m][j]);
                acc[m][n][j] = p;
                rsum[m][j] += p;
            }
    #pragma unroll
    for (int off = 1; off < 16; off <<= 1)
        #pragma unroll
        for (int m = 0; m < 2; m++)
            #pragma unroll
            for (int j = 0; j < 4; j++) rsum[m][j] += __shfl_xor(rsum[m][j], off);

    if (arow == 0) {
        #pragma unroll
        for (int m = 0; m < 2; m++)
            #pragma unroll
            for (int j = 0; j < 4; j++) {
                const int qr = (m << 4) + rbase + j;
                redm[(qr << 3) + wid] = rmax[m][j];
                reds[(qr << 3) + wid] = rsum[m][j];
            }
    }
    __syncthreads();

    float fscale[2][4];
    #pragma unroll
    for (int m = 0; m < 2; m++)
        #pragma unroll
        for (int j = 0; j < 4; j++) {
            const int qr = (m << 4) + rbase + j;
            const float* mm = redm + (qr << 3);
            const float* ss = reds + (qr << 3);
            f32x4 m0 = *(const f32x4*)mm, m1 = *(const f32x4*)(mm + 4);
            f32x4 s0 = *(const f32x4*)ss, s1 = *(const f32x4*)(ss + 4);
            float gm = fmaxf(fmaxf(fmaxf(m0[0], m0[1]), fmaxf(m0[2], m0[3])),
                             fmaxf(fmaxf(m1[0], m1[1]), fmaxf(m1[2], m1[3])));
            float S = s0[0] * __expf(m0[0] - gm) + s0[1] * __expf(m0[1] - gm) +
                      s0[2] * __expf(m0[2] - gm) + s0[3] * __expf(m0[3] - gm) +
                      s1[0] * __expf(m1[0] - gm) + s1[1] * __expf(m1[1] - gm) +
                      s1[2] * __expf(m1[2] - gm) + s1[3] * __expf(m1[3] - gm);
            fscale[m][j] = __expf(rmax[m][j] - gm) / S;
        }

    const size_t obase = (((size_t)bh << 10) + q0) << 10;
    #pragma unroll
    for (int m = 0; m < 2; m++)
        #pragma unroll
        for (int j = 0; j < 4; j++) {
            const int qr = (m << 4) + rbase + j;
            float* orow = attn + obase + ((size_t)qr << 10) + kb;
            char* prow = (char*)Plds + (qr << 11);
            const int rx = (qr & 7) << 4;
            const float iv = fscale[m][j];
            #pragma unroll
            for (int n = 0; n < 8; n++) {
                float p = acc[m][n][j] * iv;
                orow[(n << 4) + arow] = p;
                *(bf16*)(prow + ((((kb + (n << 4) + arow)) << 1) ^ rx)) = __float2bfloat16(p);
            }
        }

    asm volatile("s_waitcnt lgkmcnt(0)" ::: "memory");
    __builtin_amdgcn_s_barrier();
    __builtin_amdgcn_sched_barrier(0);

    const int qh = wid >> 2, dh = wid & 3;
    const char* pbase = (char*)Plds + (((qh << 4) + arow) << 11);
    const int prx = (arow & 7) << 4;
    const bf16* vrow = vT + ((size_t)((b << 10) + (h << 6) + (dh << 4) + arow) << 10);
    f32x4 acc2 = (f32x4){0.f, 0.f, 0.f, 0.f};
    #pragma unroll 8
    for (int kt = 0; kt < 32; kt++) {
        short8 af  = *(const short8*)(pbase + (((kt << 6) + (hi << 4)) ^ prx));
        short8 bf2 = *(const short8*)(vrow + (kt << 5) + koff);
        acc2 = __builtin_amdgcn_mfma_f32_16x16x32_bf16(af, bf2, acc2, 0, 0, 0);
    }

    #pragma unroll
    for (int j = 0; j < 4; j++) {
        const int row = q0 + (qh << 4) + rbase + j;
        ctx[((size_t)((b << 10) + row) << 10) + (h << 6) + (dh << 4) + arow] =
            __float2bfloat16(acc2[j]);
    }
}

// ---------------------------------------------------------------- launch
extern "C" void kernel_launch(void* const* d_in, const int* in_sizes, int n_in,
                              void* d_out, int out_size, void* d_ws, size_t ws_size,
                              hipStream_t stream) {
    (void)in_sizes; (void)n_in; (void)out_size; (void)ws_size;
    const float* x   = (const float*)d_in[0];
    const int*   mask= (const int*)d_in[1];
    const float* Wq  = (const float*)d_in[2];  const float* bq  = (const float*)d_in[3];
    const float* Wk  = (const float*)d_in[4];  const float* bk  = (const float*)d_in[5];
    const float* Wv  = (const float*)d_in[6];  const float* bv  = (const float*)d_in[7];
    const float* Wo  = (const float*)d_in[8];  const float* bo  = (const float*)d_in[9];
    const float* lag = (const float*)d_in[10]; const float* lab = (const float*)d_in[11];
    const float* W1  = (const float*)d_in[12]; const float* b1  = (const float*)d_in[13];
    const float* W2  = (const float*)d_in[14]; const float* b2  = (const float*)d_in[15];
    const float* lfg = (const float*)d_in[16]; const float* lfb = (const float*)d_in[17];
    const float* bffg= (const float*)d_in[18]; const float* bffb= (const float*)d_in[19];
    const float* bffm= (const float*)d_in[20]; const float* bffv= (const float*)d_in[21];
    const float* b1g = (const float*)d_in[22]; const float* b1b = (const float*)d_in[23];
    const float* b1m = (const float*)d_in[24]; const float* b1v = (const float*)d_in[25];
    const float* b2g = (const float*)d_in[26]; const float* b2b = (const float*)d_in[27];
    const float* b2m = (const float*)d_in[28]; const float* b2v = (const float*)d_in[29];

    char* ws = (char*)d_ws;
    const size_t MB = 1024 * 1024;
    bf16* wqkv_bf = (bf16*)(ws);               // 6 MB  (3072 x 1024)
    bf16* wo_bf   = (bf16*)(ws + 6 * MB);      // 2 MB
    bf16* w1_bf   = (bf16*)(ws + 8 * MB);      // 8 MB
    bf16* w2_bf   = (bf16*)(ws + 16 * MB);     // 8 MB
    float* s1  = (float*)(ws + 24 * MB); float* t1  = s1 + 1024;
    float* s2  = t1 + 1024;              float* t2  = s2 + 1024;
    float* sff = t2 + 1024;              float* tff = sff + 4096;
    bf16* x_bf   = (bf16*)(ws + 25 * MB);
    bf16* xq_bf  = (bf16*)(ws + 41 * MB);
    bf16* q_bf   = (bf16*)(ws + 57 * MB);
    bf16* k_bf   = (bf16*)(ws + 73 * MB);
    bf16* vT_bf  = (bf16*)(ws + 89 * MB);
    bf16* ctx_bf = (bf16*)(ws + 105 * MB);
    float* x1    = (float*)(ws + 121 * MB);    // 32 MB f32
    bf16* xn_bf  = (bf16*)(ws + 153 * MB);
    bf16* h_bf   = (bf16*)(ws + 169 * MB);     // 64 MB, ends at 233 MB

    float* out_x    = (float*)d_out;
    float* out_attn = out_x + (size_t)8 * 1024 * 1024;

    cast_all<<<12288, 256, 0, stream>>>(Wq, Wk, Wv, Wo, W1, W2, wqkv_bf, wo_bf, w1_bf, w2_bf);
    affine_all<<<24, 256, 0, stream>>>(b1g, b1b, b1m, b1v, b2g, b2b, b2m, b2v,
                                       bffg, bffb, bffm, bffv, s1, t1, s2, t2, sff, tff);

    // LN(x) (for q) + raw cast (for k,v)
    ln_kernel<<<8192, 256, 0, stream>>>(x, lag, lab, xq_bf, x_bf);

    // fused q/k/v projection — 768 blocks (3/CU exact), 3-slot engine
    gemm3s<M_QKV><<<dim3(24, 32), 512, 0, stream>>>(
        xq_bf, x_bf, wqkv_bf, bq, bk, bv, q_bf, k_bf, vT_bf, nullptr, nullptr, nullptr, 1024, 1024);

    // fused scores+softmax (-> d_out attn) + PV via shared LDS P (-> ctx)
    fattn_kernel<<<dim3(32, 128), 512, 0, stream>>>(q_bf, k_bf, vT_bf, mask, out_attn, ctx_bf);

    // attn_out proj + residual + bn1 -> x1 (f32) — 256 blocks, 3-slot engine
    gemm3s<M_RESBN><<<dim3(8, 32), 512, 0, stream>>>(
        ctx_bf, nullptr, wo_bf, bo, nullptr, nullptr, x1, nullptr, nullptr, x, s1, t1, 1024, 1024);

    // FFN: LN -> W1+gelu+bnff (512 blocks, 4-phase) -> W2 + residual + bn2 (256 blocks, 3-slot)
    ln_kernel<<<8192, 256, 0, stream>>>(x1, lfg, lfb, xn_bf, nullptr);
    gemm8<256, M_GELU><<<dim3(16, 32), 512, 0, stream>>>(
        xn_bf, nullptr, w1_bf, b1, nullptr, nullptr, h_bf, nullptr, nullptr, nullptr, sff, tff, 4096, 1024);
    gemm3s<M_RESBN><<<dim3(8, 32), 512, 0, stream>>>(
        h_bf, nullptr, w2_bf, b2, nullptr, nullptr, out_x, nullptr, nullptr, x1, s2, t2, 1024, 4096);
}

// Round 16
// 590.999 us; speedup vs baseline: 1.1110x; 1.0263x over previous
//
#include <hip/hip_runtime.h>
#include <hip/hip_bf16.h>
#include <math.h>

typedef __hip_bfloat16 bf16;
typedef __attribute__((ext_vector_type(8))) short short8;
typedef __attribute__((ext_vector_type(4))) short short4v;
typedef __attribute__((ext_vector_type(4))) float f32x4;

#define DEV static __device__ __forceinline__

DEV short f2bf(float f) {
    bf16 h = __float2bfloat16(f);
    return __builtin_bit_cast(short, h);
}

DEV void glds16(const void* g, void* l) {
    __builtin_amdgcn_global_load_lds((const __attribute__((address_space(1))) void*)g,
                                     (__attribute__((address_space(3))) void*)l, 16, 0, 0);
}

// ---------------------------------------------------------------- all weight casts in one kernel
__global__ __launch_bounds__(256) void cast_all(const float* __restrict__ Wq,
                                                const float* __restrict__ Wk,
                                                const float* __restrict__ Wv,
                                                const float* __restrict__ Wo,
                                                const float* __restrict__ W1,
                                                const float* __restrict__ W2,
                                                bf16* __restrict__ wqkv, bf16* __restrict__ wo,
                                                bf16* __restrict__ w1, bf16* __restrict__ w2) {
    int i = blockIdx.x * 256 + threadIdx.x;
    const float* src;
    bf16* dst;
    int si, di;
    if (i < 786432) {
        src = (i < 262144) ? Wq : (i < 524288) ? Wk : Wv;
        si = (i < 262144) ? i : (i < 524288) ? i - 262144 : i - 524288;
        dst = wqkv; di = i;
    } else if (i < 1048576) {
        src = Wo; si = i - 786432; dst = wo; di = si;
    } else if (i < 2097152) {
        src = W1; si = i - 1048576; dst = w1; di = si;
    } else {
        src = W2; si = i - 2097152; dst = w2; di = si;
    }
    f32x4 v = ((const f32x4*)src)[si];
    short4v o;
    #pragma unroll
    for (int j = 0; j < 4; j++) o[j] = f2bf(v[j]);
    ((short4v*)dst)[di] = o;
}

// ---------------------------------------------------------------- BN eval affines (bn1, bn2, bnff)
__global__ __launch_bounds__(256) void affine_all(
    const float* __restrict__ g1, const float* __restrict__ bb1, const float* __restrict__ m1, const float* __restrict__ v1,
    const float* __restrict__ g2, const float* __restrict__ bb2, const float* __restrict__ m2, const float* __restrict__ v2,
    const float* __restrict__ gf, const float* __restrict__ bbf, const float* __restrict__ mf, const float* __restrict__ vf,
    float* __restrict__ s1, float* __restrict__ t1, float* __restrict__ s2, float* __restrict__ t2,
    float* __restrict__ sf, float* __restrict__ tf) {
    int i = blockIdx.x * 256 + threadIdx.x;
    const float *g, *b, *m, *v; float *s, *t; int j;
    if (i < 1024)      { g = g1; b = bb1; m = m1; v = v1; s = s1; t = t1; j = i; }
    else if (i < 2048) { g = g2; b = bb2; m = m2; v = v2; s = s2; t = t2; j = i - 1024; }
    else               { g = gf; b = bbf; m = mf; v = vf; s = sf; t = tf; j = i - 2048; }
    float sc = g[j] * rsqrtf(v[j] + 1e-5f);
    s[j] = sc;
    t[j] = b[j] - m[j] * sc;
}

// ---------------------------------------------------------------- LayerNorm (row=1024) + optional raw cast
__global__ __launch_bounds__(256) void ln_kernel(const float* __restrict__ x,
                                                 const float* __restrict__ g,
                                                 const float* __restrict__ b,
                                                 bf16* __restrict__ lnout,
                                                 bf16* __restrict__ rawout) {
    const int row = blockIdx.x, t = threadIdx.x;
    const float* xr = x + (size_t)row * 1024;
    f32x4 v = ((const f32x4*)xr)[t];
    float s = v[0] + v[1] + v[2] + v[3];
    float sq = v[0]*v[0] + v[1]*v[1] + v[2]*v[2] + v[3]*v[3];
    #pragma unroll
    for (int off = 1; off < 64; off <<= 1) {
        s  += __shfl_xor(s, off);
        sq += __shfl_xor(sq, off);
    }
    __shared__ float ls[4], lq[4];
    if ((t & 63) == 0) { ls[t >> 6] = s; lq[t >> 6] = sq; }
    __syncthreads();
    s = ls[0] + ls[1] + ls[2] + ls[3];
    sq = lq[0] + lq[1] + lq[2] + lq[3];
    float mu = s * (1.0f / 1024.0f);
    float rs = rsqrtf(sq * (1.0f / 1024.0f) - mu * mu + 1e-5f);
    f32x4 gg = ((const f32x4*)g)[t];
    f32x4 bb = ((const f32x4*)b)[t];
    short4v o;
    #pragma unroll
    for (int j = 0; j < 4; j++) o[j] = f2bf((v[j] - mu) * rs * gg[j] + bb[j]);
    ((short4v*)(lnout + (size_t)row * 1024))[t] = o;
    if (rawout) {
        short4v r;
        #pragma unroll
        for (int j = 0; j < 4; j++) r[j] = f2bf(v[j]);
        ((short4v*)(rawout + (size_t)row * 1024))[t] = r;
    }
}

enum { M_RESBN = 0, M_GELU = 1, M_QKV = 2 };

// ================================================================ 3-slot ring 256x128 engine (all GEMMs)
// BK=64, 8 waves 2Mx4N, wave-tile 128x32 (MF=8, NF=2). LDS: A 3x32KB @0,
// B 3x16KB @98304 (144KB). Stage tile t+2 during t -> ONE vmcnt(6) + ONE
// barrier per K-tile; tile t's 6 loads were issued a full tile earlier
// (>= HBM latency cover). No intra-tile barriers: slot (t+2)%3 disjoint from
// t,t+1; entry barrier orders overwrite of slot(t-1) vs its readers.
template <int MODE>
__global__ __launch_bounds__(512, 2) void gemm3s(
    const bf16* __restrict__ A0, const bf16* __restrict__ A1, const bf16* __restrict__ Bw,
    const float* __restrict__ b0, const float* __restrict__ b1, const float* __restrict__ b2,
    void* __restrict__ o0, void* __restrict__ o1, void* __restrict__ o2,
    const float* __restrict__ res, const float* __restrict__ sa, const float* __restrict__ ta,
    int N, int K) {
    __shared__ char smem[147456];

    const int tid = threadIdx.x, lane = tid & 63, wid = tid >> 6;
    const int gx = gridDim.x;
    const int n_wg = gx * gridDim.y;
    int lin = blockIdx.y * gx + blockIdx.x;
    lin = (lin & 7) * (n_wg >> 3) + (lin >> 3);    // XCD swizzle (n_wg % 8 == 0)
    const int bn = (lin % gx) << 7, bm = (lin / gx) << 8;

    const int wr = wid >> 2, wc = wid & 3;
    const int arow = lane & 15, hi = lane >> 4;
    const int xr = arow & 7;
    const int ck0 = (hi ^ xr) << 3;
    const int ck1 = ((4 + hi) ^ xr) << 3;
    const int rowA = wr * 128 + arow;
    const int rowB = wc * 32 + arow;

    const bf16* Asel;
    if constexpr (MODE == M_QKV) Asel = (bn < 1024) ? A0 : A1;
    else                         Asel = A0;

    const int rS = tid >> 3;
    const int cXor = ((tid & 7) ^ (rS & 7)) << 3;
    const bf16* gA = Asel + (size_t)(bm + rS) * K + cXor;
    const bf16* gB = Bw   + (size_t)(bn + rS) * K + cXor;

    f32x4 acc[8][2] = {};

    auto stA = [&](int t, int i) {
        glds16(gA + (size_t)i * 64 * K + t * 64,
               smem + (t % 3) * 32768 + i * 8192 + (wid << 10));
    };
    auto stB = [&](int t, int i) {
        glds16(gB + (size_t)i * 64 * K + t * 64,
               smem + 98304 + (t % 3) * 16384 + i * 8192 + (wid << 10));
    };

    const int NT = K >> 6;
    // prologue: tiles 0 and 1 fully staged (6 issues each)
    stB(0, 0); stB(0, 1); stA(0, 0); stA(0, 2); stA(0, 1); stA(0, 3);
    stB(1, 0); stB(1, 1); stA(1, 0); stA(1, 2); stA(1, 1); stA(1, 3);

#define PHASE3(Q)                                                                             \
    do {                                                                                      \
        const short8 a00 = *(const short8*)(Ap + (rowA + (2*(Q)) * 16) * 64 + ck0);           \
        const short8 a01 = *(const short8*)(Ap + (rowA + (2*(Q)) * 16) * 64 + ck1);           \
        const short8 a10 = *(const short8*)(Ap + (rowA + (2*(Q)+1) * 16) * 64 + ck0);         \
        const short8 a11 = *(const short8*)(Ap + (rowA + (2*(Q)+1) * 16) * 64 + ck1);         \
        __builtin_amdgcn_s_setprio(1);                                                        \
        _Pragma("unroll")                                                                     \
        for (int n = 0; n < 2; n++) {                                                         \
            acc[2*(Q)][n]   = __builtin_amdgcn_mfma_f32_16x16x32_bf16(a00, bva[n], acc[2*(Q)][n], 0, 0, 0);   \
            acc[2*(Q)][n]   = __builtin_amdgcn_mfma_f32_16x16x32_bf16(a01, bvb[n], acc[2*(Q)][n], 0, 0, 0);   \
            acc[2*(Q)+1][n] = __builtin_amdgcn_mfma_f32_16x16x32_bf16(a10, bva[n], acc[2*(Q)+1][n], 0, 0, 0); \
            acc[2*(Q)+1][n] = __builtin_amdgcn_mfma_f32_16x16x32_bf16(a11, bvb[n], acc[2*(Q)+1][n], 0, 0, 0); \
        }                                                                                     \
        __builtin_amdgcn_s_setprio(0);                                                        \
    } while (0)

    for (int t = 0; t < NT; ++t) {
        const bf16* Ap = (const bf16*)(smem + (t % 3) * 32768);
        const bf16* Bp = (const bf16*)(smem + 98304 + (t % 3) * 16384);
        // one counted wait per tile: drain tile t's 6 loads (issued during t-2/prologue),
        // keep tile t+1's 6 in flight
        if (t >= NT - 1) asm volatile("s_waitcnt vmcnt(0)" ::: "memory");
        else             asm volatile("s_waitcnt vmcnt(6)" ::: "memory");
        __builtin_amdgcn_s_barrier();
        if (t + 2 < NT) { stB(t + 2, 0); stB(t + 2, 1); }
        short8 bva[2], bvb[2];
        #pragma unroll
        for (int n = 0; n < 2; n++) {
            bva[n] = *(const short8*)(Bp + (rowB + n * 16) * 64 + ck0);
            bvb[n] = *(const short8*)(Bp + (rowB + n * 16) * 64 + ck1);
        }
        PHASE3(0);
        PHASE3(1);
        if (t + 2 < NT) { stA(t + 2, 0); stA(t + 2, 2); }
        PHASE3(2);
        if (t + 2 < NT) { stA(t + 2, 1); stA(t + 2, 3); }
        PHASE3(3);
    }
#undef PHASE3

    #pragma unroll
    for (int mf = 0; mf < 8; mf++) {
        #pragma unroll
        for (int nf = 0; nf < 2; nf++) {
            const int col = bn + wc * 32 + nf * 16 + arow;
            #pragma unroll
            for (int j = 0; j < 4; j++) {
                const int row = bm + wr * 128 + mf * 16 + hi * 4 + j;
                if constexpr (MODE == M_RESBN) {
                    float v = acc[mf][nf][j] + b0[col];
                    size_t idx = (size_t)row * N + col;
                    ((float*)o0)[idx] = (res[idx] + v) * sa[col] + ta[col];
                } else if constexpr (MODE == M_GELU) {
                    float v = acc[mf][nf][j] + b0[col];
                    float ge = 0.5f * v * (1.0f + erff(v * 0.70710678118f));
                    ((bf16*)o0)[(size_t)row * N + col] = __float2bfloat16(ge * sa[col] + ta[col]);
                } else {
                    const int reg = col >> 10, c = col & 1023;
                    const float bb = (reg == 0) ? b0[c] : (reg == 1) ? b1[c] : b2[c];
                    float v = acc[mf][nf][j] + bb;
                    if (reg == 0)
                        ((bf16*)o0)[(size_t)row * 1024 + c] = __float2bfloat16(v * 0.125f);
                    else if (reg == 1)
                        ((bf16*)o1)[(size_t)row * 1024 + c] = __float2bfloat16(v);
                    else
                        ((bf16*)o2)[((size_t)(row >> 10) << 20) + ((size_t)c << 10) + (row & 1023)] =
                            __float2bfloat16(v);
                }
            }
        }
    }
}

// ---------------------------------------------------------------- fused scores+softmax+attn-write+PV
// (R13 structure; attn stores are NON-TEMPORAL: streamed once, never re-read by
// this kernel — keeps K/V resident in L2 instead of being evicted by the
// 536 MB attn write stream.)
__global__ __launch_bounds__(512, 4) void fattn_kernel(const bf16* __restrict__ q,
                                                       const bf16* __restrict__ k,
                                                       const bf16* __restrict__ vT,
                                                       const int* __restrict__ mask,
                                                       float* __restrict__ attn,
                                                       bf16* __restrict__ ctx) {
    const int bh = blockIdx.y, b = bh >> 4, h = bh & 15;
    const int q0 = blockIdx.x << 5;
    const int tid = threadIdx.x, lane = tid & 63, wid = tid >> 6;
    const int kb = wid << 7;
    const int arow = lane & 15, hi = lane >> 4, koff = hi << 3;
    const int rbase = hi << 2;

    __shared__ char smem[67584];
    bf16* Plds = (bf16*)smem;
    float* redm = (float*)(smem + 65536);
    float* reds = (float*)(smem + 66560);

    short8 qf[2], qf2[2];
    #pragma unroll
    for (int m = 0; m < 2; m++) {
        const bf16* qp = q + ((size_t)((b << 10) + q0 + (m << 4) + arow) << 10) + (h << 6);
        qf[m]  = *(const short8*)(qp + koff);
        qf2[m] = *(const short8*)(qp + 32 + koff);
    }

    f32x4 acc[2][8];
    #pragma unroll
    for (int m = 0; m < 2; m++)
        #pragma unroll
        for (int n = 0; n < 8; n++) acc[m][n] = (f32x4){0.f, 0.f, 0.f, 0.f};

    const bf16* kpBase = k + ((size_t)((b << 10) + kb + arow) << 10) + (h << 6);
    short8 kf  = *(const short8*)(kpBase + koff);
    short8 kf2 = *(const short8*)(kpBase + 32 + koff);
    #pragma unroll
    for (int n = 0; n < 8; n++) {
        short8 kfn, kf2n;
        if (n < 7) {
            const bf16* kp = kpBase + ((size_t)(n + 1) << 14);
            kfn  = *(const short8*)(kp + koff);
            kf2n = *(const short8*)(kp + 32 + koff);
        }
        acc[0][n] = __builtin_amdgcn_mfma_f32_16x16x32_bf16(qf[0],  kf,  acc[0][n], 0, 0, 0);
        acc[0][n] = __builtin_amdgcn_mfma_f32_16x16x32_bf16(qf2[0], kf2, acc[0][n], 0, 0, 0);
        acc[1][n] = __builtin_amdgcn_mfma_f32_16x16x32_bf16(qf[1],  kf,  acc[1][n], 0, 0, 0);
        acc[1][n] = __builtin_amdgcn_mfma_f32_16x16x32_bf16(qf2[1], kf2, acc[1][n], 0, 0, 0);
        kf = kfn; kf2 = kf2n;
    }

    float rmax[2][4];
    #pragma unroll
    for (int m = 0; m < 2; m++)
        #pragma unroll
        for (int j = 0; j < 4; j++) rmax[m][j] = -3.0e38f;

    #pragma unroll
    for (int n = 0; n < 8; n++) {
        const float madd = mask[(b << 10) + kb + (n << 4) + arow] ? 0.0f : -1e9f;
        #pragma unroll
        for (int m = 0; m < 2; m++)
            #pragma unroll
            for (int j = 0; j < 4; j++) {
                acc[m][n][j] += madd;
                rmax[m][j] = fmaxf(rmax[m][j], acc[m][n][j]);
            }
    }
    #pragma unroll
    for (int off = 1; off < 16; off <<= 1)
        #pragma unroll
        for (int m = 0; m < 2; m++)
            #pragma unroll
            for (int j = 0; j < 4; j++) rmax[m][j] = fmaxf(rmax[m][j], __shfl_xor(rmax[m][j], off));

    float rsum[2][4] = {};
    #pragma unroll
    for (int n = 0; n < 8; n++)
        #pragma unroll
        for (int m = 0; m < 2; m++)
            #pragma unroll
            for (int j = 0; j < 4; j++) {
                float p = __expf(acc[m][n][j] - rmax[m][j]);
                acc[m][n][j] = p;
                rsum[m][j] += p;
            }
    #pragma unroll
    for (int off = 1; off < 16; off <<= 1)
        #pragma unroll
        for (int m = 0; m < 2; m++)
            #pragma unroll
            for (int j = 0; j < 4; j++) rsum[m][j] += __shfl_xor(rsum[m][j], off);

    if (arow == 0) {
        #pragma unroll
        for (int m = 0; m < 2; m++)
            #pragma unroll
            for (int j = 0; j < 4; j++) {
                const int qr = (m << 4) + rbase + j;
                redm[(qr << 3) + wid] = rmax[m][j];
                reds[(qr << 3) + wid] = rsum[m][j];
            }
    }
    __syncthreads();

    float fscale[2][4];
    #pragma unroll
    for (int m = 0; m < 2; m++)
        #pragma unroll
        for (int j = 0; j < 4; j++) {
            const int qr = (m << 4) + rbase + j;
            const float* mm = redm + (qr << 3);
            const float* ss = reds + (qr << 3);
            f32x4 m0 = *(const f32x4*)mm, m1 = *(const f32x4*)(mm + 4);
            f32x4 s0 = *(const f32x4*)ss, s1 = *(const f32x4*)(ss + 4);
            float gm = fmaxf(fmaxf(fmaxf(m0[0], m0[1]), fmaxf(m0[2], m0[3])),
                             fmaxf(fmaxf(m1[0], m1[1]), fmaxf(m1[2], m1[3])));
            float S = s0[0] * __expf(m0[0] - gm) + s0[1] * __expf(m0[1] - gm) +
                      s0[2] * __expf(m0[2] - gm) + s0[3] * __expf(m0[3] - gm) +
                      s1[0] * __expf(m1[0] - gm) + s1[1] * __expf(m1[1] - gm) +
                      s1[2] * __expf(m1[2] - gm) + s1[3] * __expf(m1[3] - gm);
            fscale[m][j] = __expf(rmax[m][j] - gm) / S;
        }

    const size_t obase = (((size_t)bh << 10) + q0) << 10;
    #pragma unroll
    for (int m = 0; m < 2; m++)
        #pragma unroll
        for (int j = 0; j < 4; j++) {
            const int qr = (m << 4) + rbase + j;
            float* orow = attn + obase + ((size_t)qr << 10) + kb;
            char* prow = (char*)Plds + (qr << 11);
            const int rx = (qr & 7) << 4;
            const float iv = fscale[m][j];
            #pragma unroll
            for (int n = 0; n < 8; n++) {
                float p = acc[m][n][j] * iv;
                __builtin_nontemporal_store(p, orow + (n << 4) + arow);
                *(bf16*)(prow + ((((kb + (n << 4) + arow)) << 1) ^ rx)) = __float2bfloat16(p);
            }
        }

    asm volatile("s_waitcnt lgkmcnt(0)" ::: "memory");
    __builtin_amdgcn_s_barrier();
    __builtin_amdgcn_sched_barrier(0);

    const int qh = wid >> 2, dh = wid & 3;
    const char* pbase = (char*)Plds + (((qh << 4) + arow) << 11);
    const int prx = (arow & 7) << 4;
    const bf16* vrow = vT + ((size_t)((b << 10) + (h << 6) + (dh << 4) + arow) << 10);
    f32x4 acc2 = (f32x4){0.f, 0.f, 0.f, 0.f};
    #pragma unroll 8
    for (int kt = 0; kt < 32; kt++) {
        short8 af  = *(const short8*)(pbase + (((kt << 6) + (hi << 4)) ^ prx));
        short8 bf2 = *(const short8*)(vrow + (kt << 5) + koff);
        acc2 = __builtin_amdgcn_mfma_f32_16x16x32_bf16(af, bf2, acc2, 0, 0, 0);
    }

    #pragma unroll
    for (int j = 0; j < 4; j++) {
        const int row = q0 + (qh << 4) + rbase + j;
        ctx[((size_t)((b << 10) + row) << 10) + (h << 6) + (dh << 4) + arow] =
            __float2bfloat16(acc2[j]);
    }
}

// ---------------------------------------------------------------- launch
extern "C" void kernel_launch(void* const* d_in, const int* in_sizes, int n_in,
                              void* d_out, int out_size, void* d_ws, size_t ws_size,
                              hipStream_t stream) {
    (void)in_sizes; (void)n_in; (void)out_size; (void)ws_size;
    const float* x   = (const float*)d_in[0];
    const int*   mask= (const int*)d_in[1];
    const float* Wq  = (const float*)d_in[2];  const float* bq  = (const float*)d_in[3];
    const float* Wk  = (const float*)d_in[4];  const float* bk  = (const float*)d_in[5];
    const float* Wv  = (const float*)d_in[6];  const float* bv  = (const float*)d_in[7];
    const float* Wo  = (const float*)d_in[8];  const float* bo  = (const float*)d_in[9];
    const float* lag = (const float*)d_in[10]; const float* lab = (const float*)d_in[11];
    const float* W1  = (const float*)d_in[12]; const float* b1  = (const float*)d_in[13];
    const float* W2  = (const float*)d_in[14]; const float* b2  = (const float*)d_in[15];
    const float* lfg = (const float*)d_in[16]; const float* lfb = (const float*)d_in[17];
    const float* bffg= (const float*)d_in[18]; const float* bffb= (const float*)d_in[19];
    const float* bffm= (const float*)d_in[20]; const float* bffv= (const float*)d_in[21];
    const float* b1g = (const float*)d_in[22]; const float* b1b = (const float*)d_in[23];
    const float* b1m = (const float*)d_in[24]; const float* b1v = (const float*)d_in[25];
    const float* b2g = (const float*)d_in[26]; const float* b2b = (const float*)d_in[27];
    const float* b2m = (const float*)d_in[28]; const float* b2v = (const float*)d_in[29];

    char* ws = (char*)d_ws;
    const size_t MB = 1024 * 1024;
    bf16* wqkv_bf = (bf16*)(ws);               // 6 MB  (3072 x 1024)
    bf16* wo_bf   = (bf16*)(ws + 6 * MB);      // 2 MB
    bf16* w1_bf   = (bf16*)(ws + 8 * MB);      // 8 MB
    bf16* w2_bf   = (bf16*)(ws + 16 * MB);     // 8 MB
    float* s1  = (float*)(ws + 24 * MB); float* t1  = s1 + 1024;
    float* s2  = t1 + 1024;              float* t2  = s2 + 1024;
    float* sff = t2 + 1024;              float* tff = sff + 4096;
    bf16* x_bf   = (bf16*)(ws + 25 * MB);
    bf16* xq_bf  = (bf16*)(ws + 41 * MB);
    bf16* q_bf   = (bf16*)(ws + 57 * MB);
    bf16* k_bf   = (bf16*)(ws + 73 * MB);
    bf16* vT_bf  = (bf16*)(ws + 89 * MB);
    bf16* ctx_bf = (bf16*)(ws + 105 * MB);
    float* x1    = (float*)(ws + 121 * MB);    // 32 MB f32
    bf16* xn_bf  = (bf16*)(ws + 153 * MB);
    bf16* h_bf   = (bf16*)(ws + 169 * MB);     // 64 MB, ends at 233 MB

    float* out_x    = (float*)d_out;
    float* out_attn = out_x + (size_t)8 * 1024 * 1024;

    cast_all<<<12288, 256, 0, stream>>>(Wq, Wk, Wv, Wo, W1, W2, wqkv_bf, wo_bf, w1_bf, w2_bf);
    affine_all<<<24, 256, 0, stream>>>(b1g, b1b, b1m, b1v, b2g, b2b, b2m, b2v,
                                       bffg, bffb, bffm, bffv, s1, t1, s2, t2, sff, tff);

    // LN(x) (for q) + raw cast (for k,v)
    ln_kernel<<<8192, 256, 0, stream>>>(x, lag, lab, xq_bf, x_bf);

    // fused q/k/v projection — 768 blocks, 3-slot engine
    gemm3s<M_QKV><<<dim3(24, 32), 512, 0, stream>>>(
        xq_bf, x_bf, wqkv_bf, bq, bk, bv, q_bf, k_bf, vT_bf, nullptr, nullptr, nullptr, 1024, 1024);

    // fused scores+softmax (-> d_out attn, non-temporal) + PV via shared LDS P (-> ctx)
    fattn_kernel<<<dim3(32, 128), 512, 0, stream>>>(q_bf, k_bf, vT_bf, mask, out_attn, ctx_bf);

    // attn_out proj + residual + bn1 -> x1 (f32) — 256 blocks, 3-slot engine
    gemm3s<M_RESBN><<<dim3(8, 32), 512, 0, stream>>>(
        ctx_bf, nullptr, wo_bf, bo, nullptr, nullptr, x1, nullptr, nullptr, x, s1, t1, 1024, 1024);

    // FFN: LN -> W1+gelu+bnff (1024 blocks, 3-slot) -> W2 + residual + bn2 (256 blocks, 3-slot)
    ln_kernel<<<8192, 256, 0, stream>>>(x1, lfg, lfb, xn_bf, nullptr);
    gemm3s<M_GELU><<<dim3(32, 32), 512, 0, stream>>>(
        xn_bf, nullptr, w1_bf, b1, nullptr, nullptr, h_bf, nullptr, nullptr, nullptr, sff, tff, 4096, 1024);
    gemm3s<M_RESBN><<<dim3(8, 32), 512, 0, stream>>>(
        h_bf, nullptr, w2_bf, b2, nullptr, nullptr, out_x, nullptr, nullptr, x1, s2, t2, 1024, 4096);
}